// Round 2
// baseline (14919.807 us; speedup 1.0000x reference)
//
#include <hip/hip_runtime.h>
#include <hip/hip_bf16.h>
#include <hip/hip_cooperative_groups.h>
#include <math.h>

namespace cg = cooperative_groups;

#define S_ 64
#define B_ 64
#define H_ 512
#define E_ 512
#define L_ 2
#define V_ 32000

#define SB_   (S_*B_)        // 4096
#define SBE_  (S_*B_*E_)     // 2097152
#define SBH_  (S_*B_*H_)     // 2097152
#define BH_   (B_*H_)        // 32768
#define KP_   1536           // split-fp16 extended K (3 * 512)

typedef _Float16 f16x8 __attribute__((ext_vector_type(8)));
typedef _Float16 f16x4 __attribute__((ext_vector_type(4)));
typedef float    f32x4 __attribute__((ext_vector_type(4)));

// ---------------------------------------------------------------------------
// Embedding gather: x[s,b,:] = emb[tokens[s,b],:]   (float4 vectorized)
// ---------------------------------------------------------------------------
__global__ __launch_bounds__(256) void embed_k(const int* __restrict__ tok,
                                               const float* __restrict__ emb,
                                               float* __restrict__ x) {
    int idx = blockIdx.x * 256 + threadIdx.x;   // over S*B*(E/4)
    int e4 = idx & (E_/4 - 1);                  // 128 float4 per row
    int sb = idx >> 7;
    int tk = tok[sb];
    *(float4*)(x + (size_t)sb * E_ + e4 * 4) =
        *(const float4*)(emb + (size_t)tk * E_ + e4 * 4);
}

// ---------------------------------------------------------------------------
// Generic fp32 GEMM + bias (used for the 6 precompute GEMMs)
// ---------------------------------------------------------------------------
__global__ __launch_bounds__(256) void gemm_bias(
    const float* __restrict__ A, int lda,
    const float* __restrict__ W, int ldw,
    const float* __restrict__ bias,
    float* __restrict__ C, int ldc,
    int K) {
    __shared__ float As[16][68];   // transposed: As[k][m]
    __shared__ float Bs[16][68];   // Bs[k][n]

    const int tid = threadIdx.x;
    const int tx = tid & 15;       // n-tile lane
    const int ty = tid >> 4;       // m-tile lane
    const int n0 = blockIdx.x * 64;
    const int m0 = blockIdx.y * 64;

    float acc[4][4] = {};

    for (int k0 = 0; k0 < K; k0 += 16) {
        {
            int i  = tid >> 2;
            int j4 = tid & 3;
            const float4 av = *(const float4*)(A + (size_t)(m0 + i) * lda + k0 + j4 * 4);
            As[j4 * 4 + 0][i] = av.x;
            As[j4 * 4 + 1][i] = av.y;
            As[j4 * 4 + 2][i] = av.z;
            As[j4 * 4 + 3][i] = av.w;
        }
        {
            int r  = tid >> 4;
            int c4 = tid & 15;
            *(float4*)(&Bs[r][c4 * 4]) =
                *(const float4*)(W + (size_t)(k0 + r) * ldw + n0 + c4 * 4);
        }
        __syncthreads();
        #pragma unroll
        for (int kk = 0; kk < 16; kk++) {
            float4 a4 = *(float4*)(&As[kk][ty * 4]);
            float4 b4 = *(float4*)(&Bs[kk][tx * 4]);
            acc[0][0] += a4.x * b4.x; acc[0][1] += a4.x * b4.y; acc[0][2] += a4.x * b4.z; acc[0][3] += a4.x * b4.w;
            acc[1][0] += a4.y * b4.x; acc[1][1] += a4.y * b4.y; acc[1][2] += a4.y * b4.z; acc[1][3] += a4.y * b4.w;
            acc[2][0] += a4.z * b4.x; acc[2][1] += a4.z * b4.y; acc[2][2] += a4.z * b4.z; acc[2][3] += a4.z * b4.w;
            acc[3][0] += a4.w * b4.x; acc[3][1] += a4.w * b4.y; acc[3][2] += a4.w * b4.z; acc[3][3] += a4.w * b4.w;
        }
        __syncthreads();
    }

    float4 bv = *(const float4*)(bias + n0 + tx * 4);
    #pragma unroll
    for (int i = 0; i < 4; i++) {
        int row = m0 + ty * 4 + i;
        float4 out;
        out.x = acc[i][0] + bv.x;
        out.y = acc[i][1] + bv.y;
        out.z = acc[i][2] + bv.z;
        out.w = acc[i][3] + bv.w;
        *(float4*)(C + (size_t)row * ldc + n0 + tx * 4) = out;
    }
}

__device__ __forceinline__ float sigmoidf_(float xv) {
    float e = __expf(-fabsf(xv));
    float s = 1.f / (1.f + e);
    return xv >= 0.f ? s : 1.f - s;
}

// ---------------------------------------------------------------------------
// Persistent cooperative GRU layer kernel: all 64 timesteps in one launch.
// grid = 256 blocks x 256 threads (1 block/CU).
// Phase A (all 256 blocks): gate g = bid>>7 (r or z); tile = 16 b x 16 c.
//   pre = P_g[t,b,c] + sum_k h_prev[b,k] * Wg[k,c]
//   g==0: rhbuf[b,c] = sigmoid(pre) * h_prev[b,c];  g==1: zbuf = sigmoid(pre)
// grid.sync()
// Phase B (blocks 0..127): hh = tanh(Ph + sum_k rh[b,k]*Wh[k,c]);
//   hseq[t,b,c] = (1-z)*h_prev + z*hh
// grid.sync()
// h staged in LDS [16][516] (pad 4: float4-aligned, conflict-free broadcast).
// 4 interleaved k-chunk accumulators keep the FMA dep chain at 128.
// ---------------------------------------------------------------------------
__global__ __launch_bounds__(256) void gru_seq_k(
    const float* __restrict__ Pr, const float* __restrict__ Pz,
    const float* __restrict__ Ph,
    const float* __restrict__ Wr_hid, const float* __restrict__ Wz_hid,
    const float* __restrict__ Wh_hid,
    const float* __restrict__ h0,
    float* __restrict__ hseq,
    float* __restrict__ zbuf, float* __restrict__ rhbuf) {
    cg::grid_group grid = cg::this_grid();
    __shared__ float hs[16][516];

    const int bid = blockIdx.x;
    const int tid = threadIdx.x;
    const int g  = bid >> 7;
    const int bt = (bid >> 5) & 3;     // batch tile 0..3 (16 b each)
    const int ct = bid & 31;           // col tile 0..31 (16 c each)
    const int bl = tid >> 4;           // local batch 0..15
    const int c  = ct * 16 + (tid & 15);
    const int b  = bt * 16 + bl;
    const size_t o = (size_t)b * H_ + c;

    const float* WgA = g ? Wz_hid : Wr_hid;

    for (int t = 0; t < S_; t++) {
        const float* h_prev = t ? (hseq + (size_t)(t - 1) * BH_) : h0;

        // ---------------- phase A: r and z gates --------------------------
        #pragma unroll
        for (int q = 0; q < 8; q++) {
            int idx = q * 256 + tid;
            int row = idx >> 7;            // 128 float4 per 512-wide row
            int c4  = idx & 127;
            *(float4*)(&hs[row][c4 * 4]) =
                *(const float4*)(h_prev + (size_t)(bt * 16 + row) * H_ + c4 * 4);
        }
        __syncthreads();
        {
            float acc[4] = {0.f, 0.f, 0.f, 0.f};
            const float* Wp = WgA + c;
            const float4* hb4 = (const float4*)&hs[bl][0];
            #pragma unroll 2
            for (int k4 = 0; k4 < 32; k4++) {
                #pragma unroll
                for (int j = 0; j < 4; j++) {
                    float4 hv = hb4[j * 32 + k4];
                    int kb = j * 128 + k4 * 4;
                    acc[j] += Wp[(size_t)(kb + 0) * H_] * hv.x;
                    acc[j] += Wp[(size_t)(kb + 1) * H_] * hv.y;
                    acc[j] += Wp[(size_t)(kb + 2) * H_] * hv.z;
                    acc[j] += Wp[(size_t)(kb + 3) * H_] * hv.w;
                }
            }
            const float* P = (g ? Pz : Pr) + (size_t)t * BH_;
            float pre = P[o] + acc[0] + acc[1] + acc[2] + acc[3];
            float v = sigmoidf_(pre);
            if (g == 0) rhbuf[o] = v * hs[bl][c];
            else        zbuf[o]  = v;
        }
        grid.sync();

        // ---------------- phase B: candidate + update ---------------------
        if (bid < 128) {
            #pragma unroll
            for (int q = 0; q < 8; q++) {
                int idx = q * 256 + tid;
                int row = idx >> 7;
                int c4  = idx & 127;
                *(float4*)(&hs[row][c4 * 4]) =
                    *(const float4*)(rhbuf + (size_t)(bt * 16 + row) * H_ + c4 * 4);
            }
            __syncthreads();
            float acc[4] = {0.f, 0.f, 0.f, 0.f};
            const float* Wp = Wh_hid + c;
            const float4* hb4 = (const float4*)&hs[bl][0];
            #pragma unroll 2
            for (int k4 = 0; k4 < 32; k4++) {
                #pragma unroll
                for (int j = 0; j < 4; j++) {
                    float4 hv = hb4[j * 32 + k4];
                    int kb = j * 128 + k4 * 4;
                    acc[j] += Wp[(size_t)(kb + 0) * H_] * hv.x;
                    acc[j] += Wp[(size_t)(kb + 1) * H_] * hv.y;
                    acc[j] += Wp[(size_t)(kb + 2) * H_] * hv.z;
                    acc[j] += Wp[(size_t)(kb + 3) * H_] * hv.w;
                }
            }
            float pre = Ph[(size_t)t * BH_ + o] + acc[0] + acc[1] + acc[2] + acc[3];
            float hhv = tanhf(pre);
            float z  = zbuf[o];
            float hp = h_prev[o];
            hseq[(size_t)t * BH_ + o] = (1.f - z) * hp + z * hhv;
        }
        grid.sync();
    }
}

// ---------------------------------------------------------------------------
// Split-fp16 cast of the final hidden sequence (see round-1 notes):
//   A'[m,k]=fp16(x); A'[m,512+k]=fp16((x-ah)*32); A'[m,1024+k]=fp16(ah/16)
// ---------------------------------------------------------------------------
__global__ __launch_bounds__(256) void castA_k(const float* __restrict__ in,
                                               _Float16* __restrict__ A2) {
    int idx = blockIdx.x * 256 + threadIdx.x;   // over 4096 * 128
    int m = idx >> 7;
    int q = idx & 127;
    float4 xv = *(const float4*)(in + (size_t)m * H_ + q * 4);
    float xs[4] = {xv.x, xv.y, xv.z, xv.w};
    f16x4 hi, lo, sc;
    #pragma unroll
    for (int i = 0; i < 4; i++) {
        _Float16 ah = (_Float16)xs[i];
        float ahf = (float)ah;
        hi[i] = ah;
        lo[i] = (_Float16)((xs[i] - ahf) * 32.0f);
        sc[i] = (_Float16)(ahf * 0.0625f);
    }
    _Float16* row = A2 + (size_t)m * KP_ + q * 4;
    *(f16x4*)(row)        = hi;
    *(f16x4*)(row + 512)  = lo;
    *(f16x4*)(row + 1024) = sc;
}

// ---------------------------------------------------------------------------
// Split-fp16 cast + transpose of Wout [512,32000] -> Bt [32000,1536]
// ---------------------------------------------------------------------------
__global__ __launch_bounds__(256) void castB_k(const float* __restrict__ W,
                                               _Float16* __restrict__ Bt) {
    __shared__ float ws[64][68];
    const int v0 = blockIdx.x * 64;
    const int h0 = blockIdx.y * 64;
    const int tid = threadIdx.x;

    #pragma unroll
    for (int q = 0; q < 4; q++) {
        int idx = q * 256 + tid;        // over 64 h-rows x 16 float4
        int h  = idx >> 4;
        int v4 = idx & 15;
        *(float4*)(&ws[h][v4 * 4]) =
            *(const float4*)(W + (size_t)(h0 + h) * V_ + v0 + v4 * 4);
    }
    __syncthreads();

    const int v  = tid >> 2;   // 0..63
    const int hq = tid & 3;    // 0..3
    #pragma unroll
    for (int j = 0; j < 2; j++) {
        int hb = j * 32 + hq * 8;
        f16x8 hi, lo, sc;
        #pragma unroll
        for (int i = 0; i < 8; i++) {
            float wv = ws[hb + i][v];
            _Float16 bh = (_Float16)wv;
            float bhf = (float)bh;
            hi[i] = bh;
            sc[i] = (_Float16)(bhf * 0.03125f);
            lo[i] = (_Float16)((wv - bhf) * 16.0f);
        }
        _Float16* row = Bt + (size_t)(v0 + v) * KP_ + h0 + hb;
        *(f16x8*)(row)        = hi;
        *(f16x8*)(row + 512)  = sc;
        *(f16x8*)(row + 1024) = lo;
    }
}

// ---------------------------------------------------------------------------
// MFMA logits GEMM: C[4096,32000] = A'[4096,1536] @ Bt[32000,1536]^T + bout
// 128x128 tile, 4 waves, 16x16x32 f16 MFMA, BK=64, global_load_lds 16B,
// XOR-swizzled LDS. grid = (250, 32).
// ---------------------------------------------------------------------------
__global__ __launch_bounds__(256) void gemm_logits(
    const _Float16* __restrict__ Ag,   // [4096, KP_]
    const _Float16* __restrict__ Bg,   // [32000, KP_]
    const float* __restrict__ bias,    // [32000]
    float* __restrict__ C) {           // [4096, 32000]
    __shared__ __align__(16) _Float16 As[128 * 64];
    __shared__ __align__(16) _Float16 Bs[128 * 64];

    const int tid  = threadIdx.x;
    const int lane = tid & 63;
    const int w    = tid >> 6;
    const int n0   = blockIdx.x * 128;
    const int m0   = blockIdx.y * 128;
    const int wm   = (w >> 1) * 64;
    const int wn   = (w & 1) * 64;

    f32x4 acc[4][4];
    #pragma unroll
    for (int i = 0; i < 4; i++)
        #pragma unroll
        for (int j = 0; j < 4; j++)
            acc[i][j] = (f32x4){0.f, 0.f, 0.f, 0.f};

    const int grow  = lane >> 3;            // row within 8-row chunk
    const int gslot = (lane & 7) ^ grow;    // pre-swizzled global 16B slot

    for (int kt = 0; kt < KP_ / 64; ++kt) {
        const int k0 = kt * 64;
        #pragma unroll
        for (int q = 0; q < 4; ++q) {
            int ch  = w * 4 + q;            // 1KB chunk = 8 rows of 128B
            int row = ch * 8 + grow;
            const _Float16* ga = Ag + (size_t)(m0 + row) * KP_ + k0 + gslot * 8;
            const _Float16* gb = Bg + (size_t)(n0 + row) * KP_ + k0 + gslot * 8;
            __builtin_amdgcn_global_load_lds(
                (const __attribute__((address_space(1))) void*)ga,
                (__attribute__((address_space(3))) void*)(As + ch * 512), 16, 0, 0);
            __builtin_amdgcn_global_load_lds(
                (const __attribute__((address_space(1))) void*)gb,
                (__attribute__((address_space(3))) void*)(Bs + ch * 512), 16, 0, 0);
        }
        __syncthreads();

        #pragma unroll
        for (int ks = 0; ks < 2; ++ks) {
            f16x8 af[4], bf[4];
            #pragma unroll
            for (int i = 0; i < 4; ++i) {
                int arow  = wm + i * 16 + (lane & 15);
                int aslot = (ks * 4 + (lane >> 4)) ^ (arow & 7);
                af[i] = *(const f16x8*)(As + arow * 64 + aslot * 8);
                int brow  = wn + i * 16 + (lane & 15);
                int bslot = (ks * 4 + (lane >> 4)) ^ (brow & 7);
                bf[i] = *(const f16x8*)(Bs + brow * 64 + bslot * 8);
            }
            #pragma unroll
            for (int mi = 0; mi < 4; ++mi)
                #pragma unroll
                for (int nj = 0; nj < 4; ++nj)
                    acc[mi][nj] = __builtin_amdgcn_mfma_f32_16x16x32_f16(
                        af[mi], bf[nj], acc[mi][nj], 0, 0, 0);
        }
        __syncthreads();
    }

    #pragma unroll
    for (int nj = 0; nj < 4; ++nj) {
        int col = n0 + wn + nj * 16 + (lane & 15);
        float bv = bias[col];
        #pragma unroll
        for (int mi = 0; mi < 4; ++mi) {
            int rb = m0 + wm + mi * 16 + (lane >> 4) * 4;
            #pragma unroll
            for (int j = 0; j < 4; ++j)
                C[(size_t)(rb + j) * V_ + col] = acc[mi][nj][j] + bv;
        }
    }
}

// ---------------------------------------------------------------------------
extern "C" void kernel_launch(void* const* d_in, const int* in_sizes, int n_in,
                              void* d_out, int out_size, void* d_ws, size_t ws_size,
                              hipStream_t stream) {
    const int*   tokens = (const int*)  d_in[0];
    const float* hidden = (const float*)d_in[1];   // [L,B,H] zeros
    const float* emb    = (const float*)d_in[2];   // [V,E]
    const float* Wr     = (const float*)d_in[3];   // [L,E+H,H]
    const float* br     = (const float*)d_in[4];   // [L,H]
    const float* Wz     = (const float*)d_in[5];
    const float* bz     = (const float*)d_in[6];
    const float* Wh     = (const float*)d_in[7];
    const float* bh     = (const float*)d_in[8];
    const float* Wout   = (const float*)d_in[9];   // [H,V]
    const float* bout   = (const float*)d_in[10];  // [V]

    float* out = (float*)d_out;            // logits [S,B,V] then hidden [L,B,H]
    float* out_hidden = out + (size_t)SB_ * V_;

    // workspace layout (fp32 region then fp16 region)
    float* ws = (float*)d_ws;
    float* x     = ws;                 // SBE_
    float* hseq1 = x + SBE_;           // SBH_
    float* hseq2 = hseq1 + SBH_;       // SBH_
    float* Pr    = hseq2 + SBH_;       // SBH_
    float* Pz    = Pr + SBH_;          // SBH_
    float* Ph    = Pz + SBH_;          // SBH_
    float* zbuf  = Ph + SBH_;          // BH_
    float* rhbuf = zbuf + BH_;         // BH_
    _Float16* A2 = (_Float16*)(rhbuf + BH_);        // SB_ * KP_   (12.6 MB)
    _Float16* Bt = A2 + (size_t)SB_ * KP_;          // V_ * KP_    (98.3 MB)

    // 1. embedding
    embed_k<<<SBE_ / 4 / 256, 256, 0, stream>>>(tokens, emb, x);

    // 2. split-fp16 cast + transpose of Wout (independent of recurrence)
    castB_k<<<dim3(V_ / 64, H_ / 64), 256, 0, stream>>>(Wout, Bt);

    const int WL = (E_ + H_) * H_;     // per-layer weight matrix size
    const float* layer_in[2] = {x, hseq1};
    float* hseqs[2] = {hseq1, hseq2};

    for (int l = 0; l < L_; l++) {
        const float* A = layer_in[l];
        const float* Wr_l = Wr + (size_t)l * WL;
        const float* Wz_l = Wz + (size_t)l * WL;
        const float* Wh_l = Wh + (size_t)l * WL;

        // input-side contributions for all timesteps
        dim3 gpre(H_ / 64, SB_ / 64);
        gemm_bias<<<gpre, 256, 0, stream>>>(A, E_, Wr_l, H_, br + l * H_, Pr, H_, E_);
        gemm_bias<<<gpre, 256, 0, stream>>>(A, E_, Wz_l, H_, bz + l * H_, Pz, H_, E_);
        gemm_bias<<<gpre, 256, 0, stream>>>(A, E_, Wh_l, H_, bh + l * H_, Ph, H_, E_);

        // whole-layer recurrence: one cooperative launch, 64 steps
        {
            const float* a0 = Pr;
            const float* a1 = Pz;
            const float* a2 = Ph;
            const float* a3 = Wr_l + (size_t)E_ * H_;
            const float* a4 = Wz_l + (size_t)E_ * H_;
            const float* a5 = Wh_l + (size_t)E_ * H_;
            const float* a6 = hidden + (size_t)l * BH_;
            float* a7 = hseqs[l];
            float* a8 = zbuf;
            float* a9 = rhbuf;
            void* cargs[] = {&a0, &a1, &a2, &a3, &a4, &a5, &a6, &a7, &a8, &a9};
            hipLaunchCooperativeKernel((void*)gru_seq_k, dim3(256), dim3(256),
                                       cargs, 0, stream);
        }

        hipMemcpyAsync(out_hidden + (size_t)l * BH_, hseqs[l] + (size_t)(S_ - 1) * BH_,
                       (size_t)BH_ * sizeof(float), hipMemcpyDeviceToDevice, stream);
    }

    // 3. split-fp16 cast of final hidden sequence
    castA_k<<<SBE_ / 4 / 256, 256, 0, stream>>>(hseq2, A2);

    // 4. logits = A2 @ Bt^T + bout via f16 MFMA (emulated fp32 precision)
    gemm_logits<<<dim3(V_ / 128, SB_ / 128), 256, 0, stream>>>(A2, Bt, bout, out);
}